// Round 9
// baseline (54.292 us; speedup 1.0000x reference)
//
#include <hip/hip_runtime.h>
#include <hip/hip_bf16.h>

typedef __bf16 bf16;
typedef bf16  bf16x2 __attribute__((ext_vector_type(2)));
typedef bf16  bf16x4 __attribute__((ext_vector_type(4)));
typedef bf16  bf16x8 __attribute__((ext_vector_type(8)));
typedef float f32x4  __attribute__((ext_vector_type(4)));
typedef float f32x16 __attribute__((ext_vector_type(16)));

#define MFMA32(A, B, C) __builtin_amdgcn_mfma_f32_32x32x16_bf16((A), (B), (C), 0, 0, 0)

namespace {
constexpr int   kS = 2048, kHq = 16, kHkv = 8, kD = 128, kChunk = 512;
constexpr int   kKB    = 128;                            // keys per tile (4 phases)
constexpr int   kStrK  = kHkv * kD;                      // floats between keys
constexpr float kLog2e = 1.4426950408889634f;
constexpr float kScale = 0.08838834764831845f * kLog2e;  // exp2-domain softmax
constexpr float kThr   = 8.0f * kLog2e;                  // T13 threshold (log2)
}

union U32B { bf16x2 h; unsigned u; };
union PAU  { unsigned u[4]; bf16x8 v; };

// Swapped-QK^T chunked-causal GQA attention, 128-key tiles (4 phases).
// 256 blocks (b,n,hq,p) x 512 threads (8 waves x 32 q-rows).
// S^T = K*Q^T -> lane owns q = lane&31; softmax lane-local (exp2 domain).
// O^T = V^T*P^T -> q stays lane-local for rescale/divide.
__global__ __launch_bounds__(512, 2)
void attn_chunk(const float* __restrict__ Qg, const float* __restrict__ Kg,
                const float* __restrict__ Vg, float* __restrict__ Og) {
  __shared__ __attribute__((aligned(16))) bf16 ldsK[2][kKB * 128];  // [key][d] ^((key&7)<<3)
  __shared__ __attribute__((aligned(16))) bf16 ldsV[2][128 * kKB];  // [d][key] ^((d&7)<<3)

  const int t = threadIdx.x, lane = t & 63, w = t >> 6;
  const int l31 = lane & 31, hi = lane >> 5;

  // XCD grouping: 32 blocks of one (b,n) per XCD (K/V L2-local).
  const int bid = blockIdx.x;
  const int gid = (bid & 7) * 32 + (bid >> 3);
  const int p = gid & 1, hq = (gid >> 1) & 15, n = (gid >> 5) & 3, b = (gid >> 7) & 1;
  const int h = hq >> 1;

  // Balanced strips: SIMD s hosts waves {s, s+4} with needs {4,1} or {3,2}.
  const int strip  = (w < 4) ? (14 - 2 * w + p) : (2 * (w - 4) + p);
  const int need   = (strip >> 2) + 1;        // 128-key tiles this wave computes
  const int qg     = n * kChunk + strip * 32 + l31;
  const int rowoff = (strip & 3) * 32 + l31;  // q offset within diagonal tile

  // ---- Q fragments: B-operand, col=q=l31, k = dk*16 + 8*hi + j ----
  bf16x8 qf[8];
  {
    const float* qp = Qg + ((size_t)(b * kS + qg) * kHq + hq) * kD;
#pragma unroll
    for (int dk = 0; dk < 8; ++dk) {
      f32x4 x0 = *(const f32x4*)(qp + dk * 16 + 8 * hi);
      f32x4 x1 = *(const f32x4*)(qp + dk * 16 + 8 * hi + 4);
      bf16x8 v;
#pragma unroll
      for (int q = 0; q < 4; ++q) { v[q] = (bf16)(x0[q] * kScale); v[4 + q] = (bf16)(x1[q] * kScale); }
      qf[dk] = v;
    }
  }

  f32x16 o[4];  // O^T accum: d = 32*dt + (r&3)+8*(r>>2)+4*hi, col q = l31
#pragma unroll
  for (int dt = 0; dt < 4; ++dt)
#pragma unroll
    for (int r = 0; r < 16; ++r) o[dt][r] = 0.f;
  float m = -1e30f, l = 0.f;

  const float* kpz = Kg + ((size_t)(b * kS + n * kChunk) * kHkv + h) * kD;
  const float* vpz = Vg + ((size_t)(b * kS + n * kChunk) * kHkv + h) * kD;

  // staging coords (512 threads / 128-key tile):
  const int sKey = t >> 5, sD4 = t & 31;  // K: key = 16*it + sKey, it 0..7
  const int vK2 = t & 63, vW = t >> 6;    // V: keys {2vK2,2vK2+1}, d4 = 8*it + vW, it 0..3

  f32x4 kf[8], va[4], vb[4];  // T14 prefetch registers (64 VGPR)
  auto issue = [&](int kt) {
    const float* kp = kpz + (size_t)kt * kKB * kStrK;
    const float* vp = vpz + (size_t)kt * kKB * kStrK;
#pragma unroll
    for (int it = 0; it < 8; ++it)
      kf[it] = *(const f32x4*)(kp + (size_t)(16 * it + sKey) * kStrK + sD4 * 4);
#pragma unroll
    for (int it = 0; it < 4; ++it) {
      va[it] = *(const f32x4*)(vp + (size_t)(2 * vK2) * kStrK + (8 * it + vW) * 4);
      vb[it] = *(const f32x4*)(vp + (size_t)(2 * vK2 + 1) * kStrK + (8 * it + vW) * 4);
    }
  };
  auto stage = [&](int buf) {
#pragma unroll
    for (int it = 0; it < 8; ++it) {
      const int key = 16 * it + sKey;
      bf16x4 kb;
#pragma unroll
      for (int q = 0; q < 4; ++q) kb[q] = (bf16)kf[it][q];
      *(bf16x4*)&ldsK[buf][key * 128 + ((sD4 * 4) ^ ((key & 7) << 3))] = kb;
    }
#pragma unroll
    for (int it = 0; it < 4; ++it) {
#pragma unroll
      for (int q = 0; q < 4; ++q) {
        const int d = (8 * it + vW) * 4 + q;
        U32B uu; uu.h = bf16x2{(bf16)va[it][q], (bf16)vb[it][q]};
        *(unsigned*)&ldsV[buf][d * kKB + ((2 * vK2) ^ ((d & 7) << 3))] = uu.u;
      }
    }
  };

  auto compute = [&](int buf, bool diag) {
    // ---- QK^T: S^T[key][q], 32 MFMA over 128 keys ----
    f32x16 s[4];
#pragma unroll
    for (int ks = 0; ks < 4; ++ks)
#pragma unroll
      for (int r = 0; r < 16; ++r) s[ks][r] = 0.f;
    __builtin_amdgcn_s_setprio(1);
#pragma unroll
    for (int ks = 0; ks < 4; ++ks) {
      const int key = ks * 32 + l31, swz = (key & 7) << 3;
      const bf16* kb = &ldsK[buf][key * 128];
#pragma unroll
      for (int dk = 0; dk < 8; ++dk) {
        bf16x8 kfr = *(const bf16x8*)&kb[(dk * 16 + 8 * hi) ^ swz];
        s[ks] = MFMA32(kfr, qf[dk], s[ks]);
      }
    }
    __builtin_amdgcn_s_setprio(0);
    if (diag) {
#pragma unroll
      for (int ks = 0; ks < 4; ++ks)
#pragma unroll
        for (int r = 0; r < 16; ++r) {
          const int key = ks * 32 + (r & 3) + 8 * (r >> 2) + 4 * hi;
          if (key > rowoff) s[ks][r] = -1e30f;
        }
    }
    // ---- lane-local softmax, exp2 domain (q = l31; partner = lane^32) ----
    float mx = -1e30f;
#pragma unroll
    for (int ks = 0; ks < 4; ++ks)
#pragma unroll
      for (int r = 0; r < 16; ++r) mx = fmaxf(mx, s[ks][r]);
    mx = fmaxf(mx, __shfl_xor(mx, 32, 64));
    if (__any(mx > m + kThr)) {  // T13 defer-max
      const float mn = fmaxf(m, mx), c = exp2f(m - mn);
      l *= c;
#pragma unroll
      for (int dt = 0; dt < 4; ++dt)
#pragma unroll
        for (int r = 0; r < 16; ++r) o[dt][r] *= c;
      m = mn;
    }
    unsigned u[4][8];
    float lp = 0.f;
#pragma unroll
    for (int ks = 0; ks < 4; ++ks)
#pragma unroll
      for (int q = 0; q < 8; ++q) {
        const float p0 = exp2f(s[ks][2 * q] - m), p1 = exp2f(s[ks][2 * q + 1] - m);
        lp += p0 + p1;
        U32B uu; uu.h = bf16x2{(bf16)p0, (bf16)p1};
        u[ks][q] = uu.u;
      }
    l += lp;
    // ---- half-exchange: interleaved-4 ownership -> contiguous-8 B-frags ----
    unsigned rc[4][4];
#pragma unroll
    for (int ks = 0; ks < 4; ++ks)
#pragma unroll
      for (int i = 0; i < 4; ++i)
        rc[ks][i] = (unsigned)__shfl_xor((int)u[ks][(i & 1) + 4 * (i >> 1) + (hi ? 0 : 2)], 32, 64);
    bf16x8 pa[8];
#pragma unroll
    for (int ks = 0; ks < 4; ++ks)
#pragma unroll
      for (int kh = 0; kh < 2; ++kh) {
        PAU pu;
        pu.u[0] = hi ? rc[ks][2 * kh]     : u[ks][4 * kh];
        pu.u[1] = hi ? rc[ks][2 * kh + 1] : u[ks][4 * kh + 1];
        pu.u[2] = hi ? u[ks][4 * kh + 2]  : rc[ks][2 * kh];
        pu.u[3] = hi ? u[ks][4 * kh + 3]  : rc[ks][2 * kh + 1];
        pa[ks * 2 + kh] = pu.v;
      }
    // ---- PV: O^T += V^T * P^T, 32 MFMA ----
    __builtin_amdgcn_s_setprio(1);
#pragma unroll
    for (int dt = 0; dt < 4; ++dt) {
      const int d = dt * 32 + l31, swz = (d & 7) << 3;
      const bf16* vbp = &ldsV[buf][d * kKB];
#pragma unroll
      for (int ksl = 0; ksl < 8; ++ksl) {
        bf16x8 vfr = *(const bf16x8*)&vbp[(ksl * 16 + 8 * hi) ^ swz];
        o[dt] = MFMA32(vfr, pa[ksl], o[dt]);
      }
    }
    __builtin_amdgcn_s_setprio(0);
  };

  // ---- main loop: 4 phases, 1 barrier each; prefetch in flight under compute
  issue(0);
  stage(0);
  issue(1);
  __syncthreads();
#pragma unroll 1
  for (int kt = 0; kt < 4; ++kt) {
    if (kt + 1 < 4) {
      stage((kt + 1) & 1);            // consumes regs issued last phase
      if (kt + 2 < 4) issue(kt + 2);  // in flight under compute(kt)
    }
    if (kt < need) compute(kt & 1, kt + 1 == need);
    if (kt + 1 < 4) __syncthreads();
  }

  // ---- epilogue: combine partner l, divide, store O^T regs ----
  l += __shfl_xor(l, 32, 64);
  const float inv = 1.f / l;
  float* op = Og + ((size_t)(b * kS + qg) * kHq + hq) * kD;
#pragma unroll
  for (int dt = 0; dt < 4; ++dt)
#pragma unroll
    for (int rq = 0; rq < 4; ++rq) {
      f32x4 st;
#pragma unroll
      for (int rr = 0; rr < 4; ++rr) st[rr] = o[dt][4 * rq + rr] * inv;
      *(f32x4*)(op + dt * 32 + 8 * rq + 4 * hi) = st;
    }
}

extern "C" void kernel_launch(void* const* d_in, const int* in_sizes, int n_in,
                              void* d_out, int out_size, void* d_ws, size_t ws_size,
                              hipStream_t stream) {
  (void)in_sizes; (void)n_in; (void)d_ws; (void)ws_size; (void)out_size;
  const float* Q = (const float*)d_in[0];
  const float* K = (const float*)d_in[1];
  const float* V = (const float*)d_in[2];
  float* O = (float*)d_out;
  dim3 grid(256);   // (b2, n4, hq16, p2), XCD-grouped; 1 block/CU
  dim3 block(512);  // 8 waves x 32 q-rows, 128-key tiles
  hipLaunchKernelGGL(attn_chunk, grid, block, 0, stream, Q, K, V, O);
}

// Round 10
// 36.385 us; speedup vs baseline: 1.4922x; 1.4922x over previous
//
#include <hip/hip_runtime.h>
#include <hip/hip_bf16.h>

typedef __bf16 bf16;
typedef bf16  bf16x2 __attribute__((ext_vector_type(2)));
typedef bf16  bf16x4 __attribute__((ext_vector_type(4)));
typedef bf16  bf16x8 __attribute__((ext_vector_type(8)));
typedef float f32x4  __attribute__((ext_vector_type(4)));
typedef float f32x16 __attribute__((ext_vector_type(16)));

#define MFMA32(A, B, C) __builtin_amdgcn_mfma_f32_32x32x16_bf16((A), (B), (C), 0, 0, 0)

namespace {
constexpr int   kS = 2048, kHq = 16, kHkv = 8, kD = 128, kChunk = 512;
constexpr int   kStrK  = kHkv * kD;                      // floats between keys
constexpr float kLog2e = 1.4426950408889634f;
constexpr float kScale = 0.08838834764831845f * kLog2e;  // exp2-domain softmax
constexpr float kThr   = 8.0f * kLog2e;                  // T13 threshold (log2)
}

union U32B { bf16x2 h; unsigned u; };
union PAU  { unsigned u[4]; bf16x8 v; };

// lgkm-only barrier: LDS drained, VMEM prefetch stays in flight across it.
__device__ __forceinline__ void lgkm_barrier() {
  __builtin_amdgcn_sched_barrier(0);
  asm volatile("s_waitcnt lgkmcnt(0)" ::: "memory");
  __builtin_amdgcn_s_barrier();
  __builtin_amdgcn_sched_barrier(0);
}

// Swapped-QK^T chunked-causal GQA attention (R4 compute, half the barriers).
// 256 blocks (b,n,hq,p) x 512 threads (8 waves x 32 q-rows).
// 4-slot LDS ring, pipeline depth 2: compute(i) reads slot staged at i-2;
// barrier only after odd iterations -> 4 barriers/block instead of 8.
__global__ __launch_bounds__(512, 2)
void attn_chunk(const float* __restrict__ Qg, const float* __restrict__ Kg,
                const float* __restrict__ Vg, float* __restrict__ Og) {
  __shared__ __attribute__((aligned(16))) bf16 ldsK[4][64 * 128];  // [key][d] ^((key&7)<<3)
  __shared__ __attribute__((aligned(16))) bf16 ldsV[4][128 * 64];  // [d][key] ^((d&7)<<3)

  const int t = threadIdx.x, lane = t & 63, w = t >> 6;
  const int l31 = lane & 31, hi = lane >> 5;

  // XCD grouping: 32 blocks of one (b,n) per XCD (K/V L2-local).
  const int bid = blockIdx.x;
  const int gid = (bid & 7) * 32 + (bid >> 3);
  const int p = gid & 1, hq = (gid >> 1) & 15, n = (gid >> 5) & 3, b = (gid >> 7) & 1;
  const int h = hq >> 1;

  // Per-SIMD balanced strips: waves (w, w+4) need 9 tiles together.
  const int a      = (w < 4) ? (7 - 2 * w) : (2 * w - 8);
  const int need   = a + 1;
  const int strip  = 2 * a + p;
  const int qg     = n * kChunk + strip * 32 + l31;
  const int rowoff = 32 * p + l31;

  // ---- Q fragments: B-operand, col=q=l31, k = dk*16 + 8*hi + j ----
  bf16x8 qf[8];
  {
    const float* qp = Qg + ((size_t)(b * kS + qg) * kHq + hq) * kD;
#pragma unroll
    for (int dk = 0; dk < 8; ++dk) {
      f32x4 x0 = *(const f32x4*)(qp + dk * 16 + 8 * hi);
      f32x4 x1 = *(const f32x4*)(qp + dk * 16 + 8 * hi + 4);
      bf16x8 v;
#pragma unroll
      for (int q = 0; q < 4; ++q) { v[q] = (bf16)(x0[q] * kScale); v[4 + q] = (bf16)(x1[q] * kScale); }
      qf[dk] = v;
    }
  }

  f32x16 o[4];  // O^T accum: d = 32*dt + (r&3)+8*(r>>2)+4*hi, col q = l31
#pragma unroll
  for (int dt = 0; dt < 4; ++dt)
#pragma unroll
    for (int r = 0; r < 16; ++r) o[dt][r] = 0.f;
  float m = -1e30f, l = 0.f;

  const float* kpz = Kg + ((size_t)(b * kS + n * kChunk) * kHkv + h) * kD;
  const float* vpz = Vg + ((size_t)(b * kS + n * kChunk) * kHkv + h) * kD;

  // staging coords (512 threads / 64-key tile):
  const int sKey = t >> 5, sD4 = t & 31;   // K: key = 16*it + sKey
  const int vKp = t & 31, vD4h = t >> 5;   // V: keys {2vKp,2vKp+1}, d4 = 16*it + vD4h

  f32x4 kf[4], va[2], vb[2];  // ONE 32-VGPR prefetch reg set (R4 profile)
  auto issue = [&](int kt) {
    const float* kp = kpz + (size_t)kt * 64 * kStrK;
    const float* vp = vpz + (size_t)kt * 64 * kStrK;
#pragma unroll
    for (int it = 0; it < 4; ++it)
      kf[it] = *(const f32x4*)(kp + (size_t)(16 * it + sKey) * kStrK + sD4 * 4);
#pragma unroll
    for (int it = 0; it < 2; ++it) {
      va[it] = *(const f32x4*)(vp + (size_t)(2 * vKp) * kStrK + (16 * it + vD4h) * 4);
      vb[it] = *(const f32x4*)(vp + (size_t)(2 * vKp + 1) * kStrK + (16 * it + vD4h) * 4);
    }
  };
  auto stage = [&](int buf) {
#pragma unroll
    for (int it = 0; it < 4; ++it) {
      const int key = 16 * it + sKey;
      bf16x4 kb;
#pragma unroll
      for (int q = 0; q < 4; ++q) kb[q] = (bf16)kf[it][q];
      *(bf16x4*)&ldsK[buf][key * 128 + ((sD4 * 4) ^ ((key & 7) << 3))] = kb;
    }
#pragma unroll
    for (int it = 0; it < 2; ++it) {
#pragma unroll
      for (int q = 0; q < 4; ++q) {
        const int d = (16 * it + vD4h) * 4 + q;
        U32B uu; uu.h = bf16x2{(bf16)va[it][q], (bf16)vb[it][q]};
        *(unsigned*)&ldsV[buf][d * 64 + ((2 * vKp) ^ ((d & 7) << 3))] = uu.u;
      }
    }
  };

  auto compute = [&](int buf, bool diag) {
    // ---- QK^T: S^T[key][q], 16 MFMA ----
    f32x16 s[2];
#pragma unroll
    for (int ks = 0; ks < 2; ++ks)
#pragma unroll
      for (int r = 0; r < 16; ++r) s[ks][r] = 0.f;
    __builtin_amdgcn_s_setprio(1);
#pragma unroll
    for (int ks = 0; ks < 2; ++ks) {
      const int key = ks * 32 + l31, swz = (key & 7) << 3;
      const bf16* kb = &ldsK[buf][key * 128];
#pragma unroll
      for (int dk = 0; dk < 8; ++dk) {
        bf16x8 kfr = *(const bf16x8*)&kb[(dk * 16 + 8 * hi) ^ swz];
        s[ks] = MFMA32(kfr, qf[dk], s[ks]);
      }
    }
    __builtin_amdgcn_s_setprio(0);
    if (diag) {
#pragma unroll
      for (int ks = 0; ks < 2; ++ks)
#pragma unroll
        for (int r = 0; r < 16; ++r) {
          const int key = ks * 32 + (r & 3) + 8 * (r >> 2) + 4 * hi;
          if (key > rowoff) s[ks][r] = -1e30f;
        }
    }
    // ---- lane-local softmax, exp2 domain (q = l31; partner = lane^32) ----
    float mx = -1e30f;
#pragma unroll
    for (int ks = 0; ks < 2; ++ks)
#pragma unroll
      for (int r = 0; r < 16; ++r) mx = fmaxf(mx, s[ks][r]);
    mx = fmaxf(mx, __shfl_xor(mx, 32, 64));
    if (__any(mx > m + kThr)) {  // T13 defer-max
      const float mn = fmaxf(m, mx), c = exp2f(m - mn);
      l *= c;
#pragma unroll
      for (int dt = 0; dt < 4; ++dt)
#pragma unroll
        for (int r = 0; r < 16; ++r) o[dt][r] *= c;
      m = mn;
    }
    unsigned u[2][8];
    float lp = 0.f;
#pragma unroll
    for (int ks = 0; ks < 2; ++ks)
#pragma unroll
      for (int q = 0; q < 8; ++q) {
        const float p0 = exp2f(s[ks][2 * q] - m), p1 = exp2f(s[ks][2 * q + 1] - m);
        lp += p0 + p1;
        U32B uu; uu.h = bf16x2{(bf16)p0, (bf16)p1};
        u[ks][q] = uu.u;
      }
    l += lp;
    // ---- half-exchange: interleaved-4 ownership -> contiguous-8 B-frags ----
    unsigned rc[2][4];
#pragma unroll
    for (int ks = 0; ks < 2; ++ks)
#pragma unroll
      for (int i = 0; i < 4; ++i)
        rc[ks][i] = (unsigned)__shfl_xor((int)u[ks][(i & 1) + 4 * (i >> 1) + (hi ? 0 : 2)], 32, 64);
    bf16x8 pa[4];
#pragma unroll
    for (int ks = 0; ks < 2; ++ks)
#pragma unroll
      for (int kh = 0; kh < 2; ++kh) {
        PAU pu;
        pu.u[0] = hi ? rc[ks][2 * kh]     : u[ks][4 * kh];
        pu.u[1] = hi ? rc[ks][2 * kh + 1] : u[ks][4 * kh + 1];
        pu.u[2] = hi ? u[ks][4 * kh + 2]  : rc[ks][2 * kh];
        pu.u[3] = hi ? u[ks][4 * kh + 3]  : rc[ks][2 * kh + 1];
        pa[ks * 2 + kh] = pu.v;
      }
    // ---- PV: O^T += V^T * P^T, 16 MFMA ----
    __builtin_amdgcn_s_setprio(1);
#pragma unroll
    for (int dt = 0; dt < 4; ++dt) {
      const int d = dt * 32 + l31, swz = (d & 7) << 3;
      const bf16* vbp = &ldsV[buf][d * 64];
#pragma unroll
      for (int ksl = 0; ksl < 4; ++ksl) {
        bf16x8 vfr = *(const bf16x8*)&vbp[(ksl * 16 + 8 * hi) ^ swz];
        o[dt] = MFMA32(vfr, pa[ksl], o[dt]);
      }
    }
    __builtin_amdgcn_s_setprio(0);
  };

  // ---- main loop: depth-2 pipeline on a 4-slot ring, barrier every 2 iters.
  // compute(i) reads slot i&3 (staged at i-2); stage(i+2) writes (i+2)&3;
  // issue(i+3) refills the single prefetch reg set.
  issue(0);
  stage(0);
  issue(1);
  stage(1);
  issue(2);
  lgkm_barrier();
#pragma unroll 1
  for (int i = 0; i < 8; ++i) {
    if (i < need) compute(i & 3, i + 1 == need);
    if (i + 2 < 8) stage((i + 2) & 3);
    if (i + 3 < 8) issue(i + 3);
    if ((i & 1) == 1 && i < 7) lgkm_barrier();
  }

  // ---- epilogue: combine partner l, divide, store O^T regs ----
  l += __shfl_xor(l, 32, 64);
  const float inv = 1.f / l;
  float* op = Og + ((size_t)(b * kS + qg) * kHq + hq) * kD;
#pragma unroll
  for (int dt = 0; dt < 4; ++dt)
#pragma unroll
    for (int rq = 0; rq < 4; ++rq) {
      f32x4 st;
#pragma unroll
      for (int rr = 0; rr < 4; ++rr) st[rr] = o[dt][4 * rq + rr] * inv;
      *(f32x4*)(op + dt * 32 + 8 * rq + 4 * hi) = st;
    }
}

extern "C" void kernel_launch(void* const* d_in, const int* in_sizes, int n_in,
                              void* d_out, int out_size, void* d_ws, size_t ws_size,
                              hipStream_t stream) {
  (void)in_sizes; (void)n_in; (void)d_ws; (void)ws_size; (void)out_size;
  const float* Q = (const float*)d_in[0];
  const float* K = (const float*)d_in[1];
  const float* V = (const float*)d_in[2];
  float* O = (float*)d_out;
  dim3 grid(256);   // (b2, n4, hq16, p2), XCD-grouped; 1 block/CU
  dim3 block(512);  // 8 waves x 32 q-rows
  hipLaunchKernelGGL(attn_chunk, grid, block, 0, stream, Q, K, V, O);
}